// Round 1
// baseline (1232.256 us; speedup 1.0000x reference)
//
#include <hip/hip_runtime.h>

#define N_NODES 100000
#define D 64
#define N_EDGES 1200000

// --- Phase 1: edge scatter. One thread per (edge, 4-float chunk).
// Gathers float4 of source features (L3-resident, 25.6MB) and atomically
// accumulates into sums (= d_out, used as accumulator). Lane chunk 0 also
// bumps the degree counter.
__global__ __launch_bounds__(256) void scatter_add(
    const float* __restrict__ feat,
    const int* __restrict__ eidx,
    float* __restrict__ sums,
    float* __restrict__ deg)
{
    int t = blockIdx.x * blockDim.x + threadIdx.x;
    if (t >= N_EDGES * 16) return;
    int e = t >> 4;          // edge id
    int c = t & 15;          // which 4-float chunk of the 64-dim row
    int src = eidx[e];
    int dst = eidx[N_EDGES + e];
    const float4 v = *reinterpret_cast<const float4*>(feat + (size_t)src * D + c * 4);
    float* o = sums + (size_t)dst * D + c * 4;
    atomicAdd(o + 0, v.x);
    atomicAdd(o + 1, v.y);
    atomicAdd(o + 2, v.z);
    atomicAdd(o + 3, v.w);
    if (c == 0) atomicAdd(deg + dst, 1.0f);
}

// --- Phase 2: per-node output. One wave (64 lanes) per node; lane j computes
// out[n][j]. Each lane holds column j of W (128 VGPRs); the combined row
// [feat(n) || mean(n)] is broadcast lane-by-lane via __shfl with compile-time
// index (v_readlane_b32 -> SALU, overlaps the FMA pipe). No LDS at all.
// Runs in-place: `out` holds the scatter sums on entry.
__global__ __launch_bounds__(256) void sage_out(
    const float* __restrict__ feat,
    const float* __restrict__ deg,
    const float* __restrict__ W,
    const float* __restrict__ bias,
    float* __restrict__ out)
{
    const int lane = threadIdx.x & 63;
    const int wave = threadIdx.x >> 6;

    // per-lane W column j: W[k][j] = W[k*64 + j], k = 0..127
    float wcol[128];
    #pragma unroll
    for (int k = 0; k < 128; ++k) wcol[k] = W[k * 64 + lane];
    const float bj = bias[lane];

    const int stride = gridDim.x * 4;
    for (int n = blockIdx.x * 4 + wave; n < N_NODES; n += stride) {
        float f = feat[(size_t)n * 64 + lane];
        float s = out[(size_t)n * 64 + lane];   // scatter sums (in-place)
        float dg = deg[n];
        dg = dg > 1.0f ? dg : 1.0f;
        float m = s / dg;

        float acc = bj;
        #pragma unroll
        for (int k = 0; k < 64; ++k)
            acc = fmaf(__shfl(f, k), wcol[k], acc);
        #pragma unroll
        for (int k = 0; k < 64; ++k)
            acc = fmaf(__shfl(m, k), wcol[64 + k], acc);

        out[(size_t)n * 64 + lane] = acc;
    }
}

extern "C" void kernel_launch(void* const* d_in, const int* in_sizes, int n_in,
                              void* d_out, int out_size, void* d_ws, size_t ws_size,
                              hipStream_t stream) {
    const float* feat = (const float*)d_in[0];
    const int*   eidx = (const int*)d_in[1];   // edge_index [2, E] (int32 on device)
    const float* W    = (const float*)d_in[2];
    const float* bias = (const float*)d_in[3];
    float* out = (float*)d_out;
    float* deg = (float*)d_ws;                 // N_NODES floats of scratch

    // zero the accumulator (d_out doubles as neigh_sum) and degree array
    hipMemsetAsync(d_out, 0, (size_t)N_NODES * D * sizeof(float), stream);
    hipMemsetAsync(d_ws, 0, (size_t)N_NODES * sizeof(float), stream);

    const int total = N_EDGES * 16;
    scatter_add<<<(total + 255) / 256, 256, 0, stream>>>(feat, eidx, out, deg);
    sage_out<<<2048, 256, 0, stream>>>(feat, deg, W, bias, out);
}

// Round 2
// 350.622 us; speedup vs baseline: 3.5145x; 3.5145x over previous
//
#include <hip/hip_runtime.h>

#define N_NODES 100000
#define D 64
#define N_EDGES 1200000
#define SCAN_B 256
#define NB ((N_NODES + SCAN_B - 1) / SCAN_B)   // 391 blocks

// ---------- CSR build ----------

__global__ __launch_bounds__(256) void hist_deg(
    const int* __restrict__ eidx, int* __restrict__ deg)
{
    int e = blockIdx.x * blockDim.x + threadIdx.x;
    if (e >= N_EDGES) return;
    atomicAdd(&deg[eidx[N_EDGES + e]], 1);
}

// per-block exclusive scan of deg -> offs (block-local), block totals -> bsum
__global__ __launch_bounds__(SCAN_B) void scan1(
    const int* __restrict__ deg, int* __restrict__ offs, int* __restrict__ bsum)
{
    __shared__ int tmp[SCAN_B];
    int tid = threadIdx.x;
    int i = blockIdx.x * SCAN_B + tid;
    int v = (i < N_NODES) ? deg[i] : 0;
    tmp[tid] = v;
    __syncthreads();
    for (int off = 1; off < SCAN_B; off <<= 1) {
        int t = (tid >= off) ? tmp[tid - off] : 0;
        __syncthreads();
        tmp[tid] += t;
        __syncthreads();
    }
    if (i < N_NODES) offs[i] = tmp[tid] - v;          // exclusive within block
    if (tid == SCAN_B - 1) bsum[blockIdx.x] = tmp[tid];
}

// single-block exclusive scan of the 391 block sums (in place)
__global__ __launch_bounds__(512) void scan2(int* __restrict__ bsum)
{
    __shared__ int tmp[512];
    int tid = threadIdx.x;
    int v = (tid < NB) ? bsum[tid] : 0;
    tmp[tid] = v;
    __syncthreads();
    for (int off = 1; off < 512; off <<= 1) {
        int t = (tid >= off) ? tmp[tid - off] : 0;
        __syncthreads();
        tmp[tid] += t;
        __syncthreads();
    }
    if (tid < NB) bsum[tid] = tmp[tid] - v;           // exclusive
}

// add block offsets; init cursors; write sentinel
__global__ __launch_bounds__(SCAN_B) void scan3(
    int* __restrict__ offs, const int* __restrict__ bsum, int* __restrict__ cur)
{
    int i = blockIdx.x * SCAN_B + threadIdx.x;
    if (i < N_NODES) {
        int o = offs[i] + bsum[blockIdx.x];
        offs[i] = o;
        cur[i] = o;
    }
    if (i == 0) offs[N_NODES] = N_EDGES;
}

__global__ __launch_bounds__(256) void fill_csr(
    const int* __restrict__ eidx, int* __restrict__ cur, int* __restrict__ csr)
{
    int e = blockIdx.x * blockDim.x + threadIdx.x;
    if (e >= N_EDGES) return;
    int dst = eidx[N_EDGES + e];
    int pos = atomicAdd(&cur[dst], 1);
    csr[pos] = eidx[e];                               // src
}

// ---------- aggregation: wave per node, lane = feature dim ----------
// Writes the neighbor MEAN directly into out[n][lane] (no atomics).
__global__ __launch_bounds__(256) void aggregate(
    const float* __restrict__ feat,
    const int* __restrict__ offs,
    const int* __restrict__ csr,
    float* __restrict__ out)
{
    const int lane = threadIdx.x & 63;
    const int n = blockIdx.x * 4 + (threadIdx.x >> 6);
    if (n >= N_NODES) return;

    const int beg = offs[n];
    const int end = offs[n + 1];

    float s = 0.0f;
    int e = beg;
    for (; e + 4 <= end; e += 4) {
        int s0 = csr[e], s1 = csr[e + 1], s2 = csr[e + 2], s3 = csr[e + 3];
        float a = feat[(size_t)s0 * D + lane];
        float b = feat[(size_t)s1 * D + lane];
        float c = feat[(size_t)s2 * D + lane];
        float d = feat[(size_t)s3 * D + lane];
        s += (a + b) + (c + d);
    }
    for (; e < end; ++e) s += feat[(size_t)csr[e] * D + lane];

    float dg = (float)(end - beg);
    dg = dg > 1.0f ? dg : 1.0f;
    out[(size_t)n * D + lane] = s / dg;
}

// ---------- output: wave per node, lane j computes out[n][j] ----------
// Reads the mean in-place from out[], register-resident W column per lane.
__global__ __launch_bounds__(256) void sage_out(
    const float* __restrict__ feat,
    const float* __restrict__ W,
    const float* __restrict__ bias,
    float* __restrict__ out)
{
    const int lane = threadIdx.x & 63;
    const int wave = threadIdx.x >> 6;

    float wcol[128];
    #pragma unroll
    for (int k = 0; k < 128; ++k) wcol[k] = W[k * 64 + lane];
    const float bj = bias[lane];

    const int stride = gridDim.x * 4;
    for (int n = blockIdx.x * 4 + wave; n < N_NODES; n += stride) {
        float f = feat[(size_t)n * 64 + lane];
        float m = out[(size_t)n * 64 + lane];   // neighbor mean (in-place)

        float acc = bj;
        #pragma unroll
        for (int k = 0; k < 64; ++k)
            acc = fmaf(__shfl(f, k), wcol[k], acc);
        #pragma unroll
        for (int k = 0; k < 64; ++k)
            acc = fmaf(__shfl(m, k), wcol[64 + k], acc);

        out[(size_t)n * 64 + lane] = acc;
    }
}

extern "C" void kernel_launch(void* const* d_in, const int* in_sizes, int n_in,
                              void* d_out, int out_size, void* d_ws, size_t ws_size,
                              hipStream_t stream) {
    const float* feat = (const float*)d_in[0];
    const int*   eidx = (const int*)d_in[1];   // [2, E] int32 on device
    const float* W    = (const float*)d_in[2];
    const float* bias = (const float*)d_in[3];
    float* out = (float*)d_out;

    // workspace layout (ints)
    int* deg  = (int*)d_ws;                    // N_NODES
    int* offs = deg + N_NODES;                 // N_NODES + 1
    int* cur  = offs + N_NODES + 1;            // N_NODES
    int* bsum = cur + N_NODES;                 // 512
    int* csr  = bsum + 512;                    // N_EDGES

    hipMemsetAsync(deg, 0, (size_t)N_NODES * sizeof(int), stream);

    hist_deg<<<(N_EDGES + 255) / 256, 256, 0, stream>>>(eidx, deg);
    scan1<<<NB, SCAN_B, 0, stream>>>(deg, offs, bsum);
    scan2<<<1, 512, 0, stream>>>(bsum);
    scan3<<<NB, SCAN_B, 0, stream>>>(offs, bsum, cur);
    fill_csr<<<(N_EDGES + 255) / 256, 256, 0, stream>>>(eidx, cur, csr);

    aggregate<<<(N_NODES + 3) / 4, 256, 0, stream>>>(feat, offs, csr, out);
    sage_out<<<2048, 256, 0, stream>>>(feat, W, bias, out);
}

// Round 3
// 246.916 us; speedup vs baseline: 4.9906x; 1.4200x over previous
//
#include <hip/hip_runtime.h>

#define N_NODES 100000
#define D 64
#define N_EDGES 1200000
#define SCAN_B 256
#define NB ((N_NODES + SCAN_B - 1) / SCAN_B)   // 391 blocks
#define XS 132   // padded X stride in floats (16B-aligned rows, 2-way banks)

// ---------- CSR build ----------

__global__ __launch_bounds__(256) void hist_deg(
    const int* __restrict__ eidx, int* __restrict__ deg)
{
    int e = blockIdx.x * blockDim.x + threadIdx.x;
    if (e >= N_EDGES) return;
    atomicAdd(&deg[eidx[N_EDGES + e]], 1);
}

__global__ __launch_bounds__(SCAN_B) void scan1(
    const int* __restrict__ deg, int* __restrict__ offs, int* __restrict__ bsum)
{
    __shared__ int tmp[SCAN_B];
    int tid = threadIdx.x;
    int i = blockIdx.x * SCAN_B + tid;
    int v = (i < N_NODES) ? deg[i] : 0;
    tmp[tid] = v;
    __syncthreads();
    for (int off = 1; off < SCAN_B; off <<= 1) {
        int t = (tid >= off) ? tmp[tid - off] : 0;
        __syncthreads();
        tmp[tid] += t;
        __syncthreads();
    }
    if (i < N_NODES) offs[i] = tmp[tid] - v;
    if (tid == SCAN_B - 1) bsum[blockIdx.x] = tmp[tid];
}

__global__ __launch_bounds__(512) void scan2(int* __restrict__ bsum)
{
    __shared__ int tmp[512];
    int tid = threadIdx.x;
    int v = (tid < NB) ? bsum[tid] : 0;
    tmp[tid] = v;
    __syncthreads();
    for (int off = 1; off < 512; off <<= 1) {
        int t = (tid >= off) ? tmp[tid - off] : 0;
        __syncthreads();
        tmp[tid] += t;
        __syncthreads();
    }
    if (tid < NB) bsum[tid] = tmp[tid] - v;
}

__global__ __launch_bounds__(SCAN_B) void scan3(
    int* __restrict__ offs, const int* __restrict__ bsum, int* __restrict__ cur)
{
    int i = blockIdx.x * SCAN_B + threadIdx.x;
    if (i < N_NODES) {
        int o = offs[i] + bsum[blockIdx.x];
        offs[i] = o;
        cur[i] = o;
    }
    if (i == 0) offs[N_NODES] = N_EDGES;
}

__global__ __launch_bounds__(256) void fill_csr(
    const int* __restrict__ eidx, int* __restrict__ cur, int* __restrict__ csr)
{
    int e = blockIdx.x * blockDim.x + threadIdx.x;
    if (e >= N_EDGES) return;
    int dst = eidx[N_EDGES + e];
    int pos = atomicAdd(&cur[dst], 1);
    csr[pos] = eidx[e];
}

// ---------- aggregation: wave per node, lane = feature dim ----------
__global__ __launch_bounds__(256) void aggregate(
    const float* __restrict__ feat,
    const int* __restrict__ offs,
    const int* __restrict__ csr,
    float* __restrict__ out)
{
    const int lane = threadIdx.x & 63;
    const int n = blockIdx.x * 4 + (threadIdx.x >> 6);
    if (n >= N_NODES) return;

    const int beg = offs[n];
    const int end = offs[n + 1];

    float s = 0.0f;
    int e = beg;
    for (; e + 8 <= end; e += 8) {
        int i0 = csr[e], i1 = csr[e+1], i2 = csr[e+2], i3 = csr[e+3];
        int i4 = csr[e+4], i5 = csr[e+5], i6 = csr[e+6], i7 = csr[e+7];
        float a0 = feat[(size_t)i0 * D + lane];
        float a1 = feat[(size_t)i1 * D + lane];
        float a2 = feat[(size_t)i2 * D + lane];
        float a3 = feat[(size_t)i3 * D + lane];
        float a4 = feat[(size_t)i4 * D + lane];
        float a5 = feat[(size_t)i5 * D + lane];
        float a6 = feat[(size_t)i6 * D + lane];
        float a7 = feat[(size_t)i7 * D + lane];
        s += ((a0 + a1) + (a2 + a3)) + ((a4 + a5) + (a6 + a7));
    }
    for (; e < end; ++e) s += feat[(size_t)csr[e] * D + lane];

    float dg = (float)(end - beg);
    dg = dg > 1.0f ? dg : 1.0f;
    out[(size_t)n * D + lane] = s / dg;
}

// ---------- fused linear: LDS-tiled GEMM, block = 64 nodes x 64 cols ----------
// X tile [64][XS] holds [feat || mean]; W staged raw [128][64].
// Thread (ng,cg) computes 4 nodes x 4 cols. Reads mean in-place from out[],
// writes result back to out[] (block touches only its own rows; sync between).
__global__ __launch_bounds__(256) void sage_gemm(
    const float* __restrict__ feat,
    const float* __restrict__ W,
    const float* __restrict__ bias,
    float* __restrict__ out)
{
    __shared__ float X[64 * XS];
    __shared__ float Ws[128 * 64];

    const int tid = threadIdx.x;
    const int nb  = blockIdx.x * 64;

    // stage W: 8192 floats = 2048 float4, 8 per thread (coalesced)
    {
        const float4* Wv  = (const float4*)W;
        float4* Wsv = (float4*)Ws;
        #pragma unroll
        for (int r = 0; r < 8; ++r)
            Wsv[r * 256 + tid] = Wv[r * 256 + tid];
    }
    // stage X: [feat || mean], float4 per (node, k-chunk)
    {
        const int sn = tid >> 4;    // 0..15
        const int kc = tid & 15;    // 0..15
        #pragma unroll
        for (int r = 0; r < 4; ++r) {
            int node = r * 16 + sn;
            int gn = nb + node;
            float4 f = make_float4(0.f, 0.f, 0.f, 0.f);
            float4 m = make_float4(0.f, 0.f, 0.f, 0.f);
            if (gn < N_NODES) {
                f = *(const float4*)(feat + (size_t)gn * 64 + kc * 4);
                m = *(const float4*)(out  + (size_t)gn * 64 + kc * 4);
            }
            *(float4*)(X + node * XS + kc * 4)      = f;
            *(float4*)(X + node * XS + 64 + kc * 4) = m;
        }
    }
    __syncthreads();

    const int ng = tid >> 4;   // node group 0..15
    const int cg = tid & 15;   // col group 0..15

    const float4 b4 = *(const float4*)(bias + cg * 4);
    float acc[4][4];
    #pragma unroll
    for (int i = 0; i < 4; ++i) {
        acc[i][0] = b4.x; acc[i][1] = b4.y; acc[i][2] = b4.z; acc[i][3] = b4.w;
    }

    const float* x0p = X + (ng * 4 + 0) * XS;
    const float* x1p = X + (ng * 4 + 1) * XS;
    const float* x2p = X + (ng * 4 + 2) * XS;
    const float* x3p = X + (ng * 4 + 3) * XS;
    const float4* Wrow = (const float4*)Ws;   // [k][16 float4]

    #pragma unroll 8
    for (int k = 0; k < 128; ++k) {
        float4 w4 = Wrow[k * 16 + cg];
        float x0 = x0p[k];
        float x1 = x1p[k];
        float x2 = x2p[k];
        float x3 = x3p[k];
        acc[0][0] = fmaf(x0, w4.x, acc[0][0]);
        acc[0][1] = fmaf(x0, w4.y, acc[0][1]);
        acc[0][2] = fmaf(x0, w4.z, acc[0][2]);
        acc[0][3] = fmaf(x0, w4.w, acc[0][3]);
        acc[1][0] = fmaf(x1, w4.x, acc[1][0]);
        acc[1][1] = fmaf(x1, w4.y, acc[1][1]);
        acc[1][2] = fmaf(x1, w4.z, acc[1][2]);
        acc[1][3] = fmaf(x1, w4.w, acc[1][3]);
        acc[2][0] = fmaf(x2, w4.x, acc[2][0]);
        acc[2][1] = fmaf(x2, w4.y, acc[2][1]);
        acc[2][2] = fmaf(x2, w4.z, acc[2][2]);
        acc[2][3] = fmaf(x2, w4.w, acc[2][3]);
        acc[3][0] = fmaf(x3, w4.x, acc[3][0]);
        acc[3][1] = fmaf(x3, w4.y, acc[3][1]);
        acc[3][2] = fmaf(x3, w4.z, acc[3][2]);
        acc[3][3] = fmaf(x3, w4.w, acc[3][3]);
    }

    #pragma unroll
    for (int i = 0; i < 4; ++i) {
        int gn = nb + ng * 4 + i;
        if (gn < N_NODES) {
            float4 o = make_float4(acc[i][0], acc[i][1], acc[i][2], acc[i][3]);
            *(float4*)(out + (size_t)gn * 64 + cg * 4) = o;
        }
    }
}

extern "C" void kernel_launch(void* const* d_in, const int* in_sizes, int n_in,
                              void* d_out, int out_size, void* d_ws, size_t ws_size,
                              hipStream_t stream) {
    const float* feat = (const float*)d_in[0];
    const int*   eidx = (const int*)d_in[1];
    const float* W    = (const float*)d_in[2];
    const float* bias = (const float*)d_in[3];
    float* out = (float*)d_out;

    int* deg  = (int*)d_ws;                    // N_NODES
    int* offs = deg + N_NODES;                 // N_NODES + 1
    int* cur  = offs + N_NODES + 1;            // N_NODES
    int* bsum = cur + N_NODES;                 // 512
    int* csr  = bsum + 512;                    // N_EDGES

    hipMemsetAsync(deg, 0, (size_t)N_NODES * sizeof(int), stream);

    hist_deg<<<(N_EDGES + 255) / 256, 256, 0, stream>>>(eidx, deg);
    scan1<<<NB, SCAN_B, 0, stream>>>(deg, offs, bsum);
    scan2<<<1, 512, 0, stream>>>(bsum);
    scan3<<<NB, SCAN_B, 0, stream>>>(offs, bsum, cur);
    fill_csr<<<(N_EDGES + 255) / 256, 256, 0, stream>>>(eidx, cur, csr);

    aggregate<<<(N_NODES + 3) / 4, 256, 0, stream>>>(feat, offs, csr, out);
    sage_gemm<<<(N_NODES + 63) / 64, 256, 0, stream>>>(feat, W, bias, out);
}